// Round 11
// baseline (140.913 us; speedup 1.0000x reference)
//
#include <hip/hip_runtime.h>
#include <cmath>
#include <complex>

// sr=16000, band 500-7000, order 8 -> 16 poles = 8 real 2nd-order sections.
#define NB    32
#define LX    262144
#define PAD   51                      // padlen = 3*17
#define LTOT  (LX + 2 * PAD)          // 262246
#define CM    32                      // samples per chunk (= per lane)
#define F_PAD 1946                    // zero-input front pad
#define LPAD  (LTOT + F_PAD)          // 264192 = 129 * 2048 (wave-tile aligned)
#define WT    2048                    // samples per wave-tile (64 lanes * 32)
#define NT    (LPAD / WT)             // 129 wave-tiles per row
#define WPB   4                       // waves per block (independent)
#define NBX   ((NT + WPB - 1) / WPB)  // 33 blocks per row
#define NP    8
#define LDSR  34                      // floats per LDS lane-row (proven layout)

struct CoeffsS { float a1[NP], a2[NP], b0[NP], b1[NP], gss[NP], c0; };
// lv[k][q] = (A_q^CM)^(2^k) = M0^(2^k), k=0..6.  lv[6] = M0^64 = wave-tile mat
struct LvS { float lv[7][NP][4]; };

// ---------------------------------------------------------------------------
// init: build mt[l*8+q] = M0^l for lane offsets l=0..63 (binary exp, f32).
__global__ void k_init(float4* __restrict__ mt, LvS L) {
    int id = blockIdx.x * 256 + threadIdx.x;
    if (id >= 512) return;
    int t = id >> 3, q = id & 7;
    float m0 = 1.f, m1 = 0.f, m2 = 0.f, m3 = 1.f;
    for (int k = 0; k < 6; k++)
        if ((t >> k) & 1) {
            float a0 = L.lv[k][q][0], a1 = L.lv[k][q][1];
            float a2 = L.lv[k][q][2], a3 = L.lv[k][q][3];
            float n0 = a0 * m0 + a1 * m2, n1 = a0 * m1 + a1 * m3;
            float n2 = a2 * m0 + a3 * m2, n3 = a2 * m1 + a3 * m3;
            m0 = n0; m1 = n1; m2 = n2; m3 = n3;
        }
    mt[id] = make_float4(m0, m1, m2, m3);
}

// ---------------------------------------------------------------------------
// u-loader pass A: chunk c covers t' in [c*32, c*32+32), real t = t' - F_PAD.
__device__ __forceinline__ void load_uA(const float* __restrict__ x,
                                        float base, int c, float (&u)[CM]) {
    int t0 = c * CM - F_PAD;
    if (t0 >= PAD && t0 + CM <= PAD + LX) {
        const float* xs = x + (t0 - PAD);
#pragma unroll
        for (int m = 0; m < CM / 4; m++) {
            float4 v = *reinterpret_cast<const float4*>(xs + 4 * m);
            u[4 * m] = v.x - base; u[4 * m + 1] = v.y - base;
            u[4 * m + 2] = v.z - base; u[4 * m + 3] = v.w - base;
        }
    } else {
#pragma unroll
        for (int i = 0; i < CM; i++) {
            int t = t0 + i;
            float uu;
            if (t < 0) uu = 0.f;                        // front pad
            else {
                float e;
                if (t < PAD)            e = 2.0f * x[0] - x[PAD - t];
                else if (t < PAD + LX)  e = x[t - PAD];
                else                    e = 2.0f * x[LX - 1] - x[2 * LX + PAD - 2 - t];
                uu = e - base;
            }
            u[i] = uu;
        }
    }
}

// local chunk recurrence from zero state
__device__ __forceinline__ void local_states(const float (&u)[CM], const CoeffsS& C,
                                             float (&w1)[NP], float (&w2)[NP]) {
#pragma unroll
    for (int q = 0; q < NP; q++) { w1[q] = 0.f; w2[q] = 0.f; }
#pragma unroll
    for (int i = 0; i < CM; i++) {
        float uu = u[i];
#pragma unroll
        for (int q = 0; q < NP; q++) {
            float wt = fmaf(C.a1[q], w1[q], fmaf(C.a2[q], w2[q], uu));
            w2[q] = w1[q]; w1[q] = wt;
        }
    }
}

// wave-level inclusive affine scan over 64 chunk states (shfl, no barriers)
__device__ __forceinline__ void wave_scan_fwd(int l, const LvS& L,
                                              float (&w1)[NP], float (&w2)[NP]) {
#pragma unroll
    for (int k = 0; k < 6; k++) {
        int d = 1 << k;
#pragma unroll
        for (int q = 0; q < NP; q++) {
            float o1 = __shfl_up(w1[q], d);
            float o2 = __shfl_up(w2[q], d);
            if (l >= d) {
                w1[q] = fmaf(L.lv[k][q][0], o1, fmaf(L.lv[k][q][1], o2, w1[q]));
                w2[q] = fmaf(L.lv[k][q][2], o1, fmaf(L.lv[k][q][3], o2, w2[q]));
            }
        }
    }
}

// reverse-order wave scan: sequence position = 63 - lane
__device__ __forceinline__ void wave_scan_rev(int l, const LvS& L,
                                              float (&w1)[NP], float (&w2)[NP]) {
#pragma unroll
    for (int k = 0; k < 6; k++) {
        int d = 1 << k;
#pragma unroll
        for (int q = 0; q < NP; q++) {
            float o1 = __shfl_down(w1[q], d);
            float o2 = __shfl_down(w2[q], d);
            if (l + d <= 63) {
                w1[q] = fmaf(L.lv[k][q][0], o1, fmaf(L.lv[k][q][1], o2, w1[q]));
                w2[q] = fmaf(L.lv[k][q][2], o1, fmaf(L.lv[k][q][3], o2, w2[q]));
            }
        }
    }
}

// ---------------------------------------------------------------------------
// K1 (pass A): per-wave-tile aggregates from zero init. No LDS, no barriers.
__global__ __launch_bounds__(256) void k_aggA(const float* __restrict__ audio,
                                              float2* __restrict__ agg,
                                              CoeffsS C, LvS L) {
    int tid = threadIdx.x, wv = tid >> 6, l = tid & 63;
    int w = blockIdx.x * WPB + wv, b = blockIdx.y;
    if (w >= NT) return;
    const float* x = audio + (size_t)b * LX;
    float base = 2.0f * x[0] - x[PAD];
    float u[CM];
    load_uA(x, base, w * 64 + l, u);
    float w1[NP], w2[NP];
    local_states(u, C, w1, w2);
    wave_scan_fwd(l, L, w1, w2);
    if (l == 63) {
#pragma unroll
        for (int q = 0; q < NP; q++)
            agg[(size_t)(b * NT + w) * NP + q] = make_float2(w1[q], w2[q]);
    }
}

// ---------------------------------------------------------------------------
// K2: per-row serial walk over NT tile aggregates -> exclusive prefixes X.
// CORR=1 (pass B): subtract base*gss from each raw aggregate (linearity).
template <int CORR>
__global__ void k_prefix(const float2* __restrict__ agg,
                         float2* __restrict__ xpre,
                         const float* __restrict__ ybuf, CoeffsS C, LvS L) {
    int b = blockIdx.x, q = threadIdx.x;
    if (q >= NP) return;
    float B0 = L.lv[6][q][0], B1 = L.lv[6][q][1];
    float B2 = L.lv[6][q][2], B3 = L.lv[6][q][3];
    float cg = 0.f;
    if (CORR) cg = ybuf[(size_t)b * LPAD] * C.gss[q];
    float X1 = 0.f, X2 = 0.f;
    for (int t = 0; t < NT; t++) {
        xpre[(size_t)(b * NT + t) * NP + q] = make_float2(X1, X2);
        float2 f = agg[(size_t)(b * NT + t) * NP + q];
        float n1 = fmaf(B0, X1, fmaf(B1, X2, f.x - cg));
        float n2 = fmaf(B2, X1, fmaf(B3, X2, f.y - cg));
        X1 = n1; X2 = n2;
    }
}

// ---------------------------------------------------------------------------
// K3: wave-autonomous filter pass. local states -> wave scan -> entry state
// from precomputed X -> replay -> per-wave LDS stage -> coalesced store.
// PASS 0: in=audio -> ybuf reversed; also emits raw pass-B tile aggregates.
// PASS 1: in=ybuf -> final out (un-reverse + trim PAD).
template <int PASS>
__global__ __launch_bounds__(256) void k_full(const float* __restrict__ in,
                                              float* __restrict__ outp,
                                              const float2* __restrict__ xpre,
                                              float2* __restrict__ aggB,
                                              const float4* __restrict__ mt,
                                              CoeffsS C, LvS L) {
    __shared__ __align__(16) float lds[WPB * 64 * LDSR];
    int tid = threadIdx.x, wv = tid >> 6, l = tid & 63;
    int w = blockIdx.x * WPB + wv, b = blockIdx.y;
    if (w >= NT) return;
    float* my = lds + wv * (64 * LDSR);

    // ---- load u ----
    float u[CM];
    if (PASS == 0) {
        const float* x = in + (size_t)b * LX;
        float base = 2.0f * x[0] - x[PAD];
        load_uA(x, base, w * 64 + l, u);
    } else {
        const float* yb = in + (size_t)b * LPAD;
        float base = yb[0];              // = y[LTOT-1]
        const float* ys = yb + (size_t)(w * 64 + l) * CM;
#pragma unroll
        for (int m = 0; m < CM / 4; m++) {
            float4 v = *reinterpret_cast<const float4*>(ys + 4 * m);
            u[4 * m] = v.x - base; u[4 * m + 1] = v.y - base;
            u[4 * m + 2] = v.z - base; u[4 * m + 3] = v.w - base;
        }
    }

    // ---- local states + wave scan (registers only) ----
    float w1[NP], w2[NP];
    local_states(u, C, w1, w2);
    wave_scan_fwd(l, L, w1, w2);

    // exclusive prefix within wave
    float e1[NP], e2[NP];
#pragma unroll
    for (int q = 0; q < NP; q++) {
        float a = __shfl_up(w1[q], 1), bb = __shfl_up(w2[q], 1);
        e1[q] = (l == 0) ? 0.f : a;
        e2[q] = (l == 0) ? 0.f : bb;
    }

    // tile entry state X (precomputed), broadcast across lanes
    float2 xv = xpre[(size_t)(b * NT + w) * NP + (l & 7)];
    float X1[NP], X2[NP];
#pragma unroll
    for (int q = 0; q < NP; q++) { X1[q] = __shfl(xv.x, q); X2[q] = __shfl(xv.y, q); }

    // entry = E + M0^l * X; replay u -> y
#pragma unroll
    for (int q = 0; q < NP; q++) {
        float4 m4 = mt[l * NP + q];
        w1[q] = fmaf(m4.x, X1[q], fmaf(m4.y, X2[q], e1[q]));
        w2[q] = fmaf(m4.z, X1[q], fmaf(m4.w, X2[q], e2[q]));
    }
#pragma unroll
    for (int i = 0; i < CM; i++) {
        float uu = u[i];
        float y = C.c0 * uu;
#pragma unroll
        for (int q = 0; q < NP; q++) {
            float wt = fmaf(C.a1[q], w1[q], fmaf(C.a2[q], w2[q], uu));
            y = fmaf(C.b0[q], wt, fmaf(C.b1[q], w1[q], y));
            w2[q] = w1[q]; w1[q] = wt;
        }
        u[i] = y;
    }

    if (PASS == 0) {
        // ---- fused raw pass-B states: reverse recurrence + reverse scan ----
        float t1[NP], t2[NP];
#pragma unroll
        for (int q = 0; q < NP; q++) { t1[q] = 0.f; t2[q] = 0.f; }
#pragma unroll
        for (int i = CM - 1; i >= 0; --i) {
            float wvv = u[i];
#pragma unroll
            for (int q = 0; q < NP; q++) {
                float wt = fmaf(C.a1[q], t1[q], fmaf(C.a2[q], t2[q], wvv));
                t2[q] = t1[q]; t1[q] = wt;
            }
        }
        wave_scan_rev(l, L, t1, t2);     // lane 0 = full reverse aggregate
        if (l == 0) {
#pragma unroll
            for (int q = 0; q < NP; q++)
                aggB[(size_t)(b * NT + (NT - 1 - w)) * NP + q] =
                    make_float2(t1[q], t2[q]);
        }
    }

    // ---- stage y to own LDS region (same-wave: no barrier needed) ----
    if (PASS == 0) {
#pragma unroll
        for (int k = 0; k < CM / 2; k++)
            *reinterpret_cast<float2*>(&my[l * LDSR + 2 * k]) =
                make_float2(u[2 * k], u[2 * k + 1]);
        // coalesced REVERSED store of this wave's 2048 samples
        float4* yb4 = reinterpret_cast<float4*>(
            outp + (size_t)b * LPAD + (size_t)(NT - 1 - w) * WT);
#pragma unroll
        for (int k = 0; k < 8; k++) {
            int o4 = l + 64 * k;             // 0..511
            int ts = 63 - (o4 >> 3);
            int ih = 31 - 4 * (o4 & 7);
            float2 a  = *reinterpret_cast<const float2*>(&my[ts * LDSR + ih - 1]);
            float2 b2 = *reinterpret_cast<const float2*>(&my[ts * LDSR + ih - 3]);
            yb4[o4] = make_float4(a.y, a.x, b2.y, b2.x);
        }
    } else {
#pragma unroll
        for (int i = 0; i < CM; i++) my[l * LDSR + i] = u[i];
        // out[j] = w[s], j = 262194 - (w*2048 + s)  (un-reverse + trim PAD)
        float* ob = outp + (size_t)b * LX;
        int J0 = (LTOT - 1 - PAD) - w * WT;
#pragma unroll
        for (int it = 0; it < CM; it++) {
            int o = it * 64 + l;
            int j = J0 - o;
            if (j >= 0 && j < LX)
                ob[j] = my[(o >> 5) * LDSR + (o & 31)];
        }
    }
}

// ---------------------------------------------------------------------------
// Host: scipy butter(8,[500,7000]/8000,'bandpass') -> real 2nd-order sections
// + chunk-transition (A^32) power levels lv[0..6] + steady-state gss (f64).
static void compute_coeffs(CoeffsS& C, LvS& L) {
    using cd = std::complex<double>;
    const int N = 8;
    const double sr = 16000.0, lo = 500.0, hi = 7000.0, fs = 2.0;
    double w0 = 2.0 * fs * std::tan(M_PI * (2.0 * lo / sr) / fs);
    double w1 = 2.0 * fs * std::tan(M_PI * (2.0 * hi / sr) / fs);
    double bw = w1 - w0, wo = std::sqrt(w0 * w1);
    cd pbp[16];
    for (int k = 0; k < N; k++) {
        int m = -N + 1 + 2 * k;
        cd pl = -std::exp(cd(0.0, M_PI * m / (2.0 * N)));
        pl *= bw / 2.0;
        cd s = std::sqrt(pl * pl - cd(wo * wo, 0.0));
        pbp[k] = pl + s; pbp[k + N] = pl - s;
    }
    double kbp = std::pow(bw, (double)N);
    const double fs2 = 4.0;
    cd pd[16], denom = 1.0;
    for (int i = 0; i < 16; i++) {
        pd[i] = (cd(fs2, 0.0) + pbp[i]) / (cd(fs2, 0.0) - pbp[i]);
        denom *= (cd(fs2, 0.0) - pbp[i]);
    }
    double kd = kbp * std::real(cd(std::pow(fs2, 8.0), 0.0) / denom);
    cd prodp = 1.0;
    for (int i = 0; i < 16; i++) prodp *= pd[i];
    cd c0 = cd(kd, 0.0) / prodp;
    int n = 0;
    for (int i = 0; i < 16; i++) {
        if (pd[i].imag() <= 0.0) continue;
        cd inv = 1.0 / pd[i];
        cd t1 = cd(1.0, 0.0) - inv, t2 = cd(1.0, 0.0) + inv;
        cd numr = cd(kd, 0.0);
        for (int k = 0; k < 8; k++) numr *= t1;
        for (int k = 0; k < 8; k++) numr *= t2;
        cd den = 1.0;
        for (int j = 0; j < 16; j++)
            if (j != i) den *= (cd(1.0, 0.0) - pd[j] * inv);
        cd r2 = 2.0 * numr / den;             // conjugate pair folded
        if (n < NP) {
            double a1 = 2.0 * pd[i].real();
            double a2 = -std::norm(pd[i]);
            C.a1[n] = (float)a1; C.a2[n] = (float)a2;
            C.b0[n] = (float)r2.real();
            C.b1[n] = (float)(-(r2.real() * pd[i].real() + r2.imag() * pd[i].imag()));
            C.gss[n] = (float)(1.0 / (1.0 - a1 - a2));   // const-input steady state
            double M[4] = { a1, a2, 1.0, 0.0 };          // A = [[a1,a2],[1,0]]
            for (int s = 0; s < 5; s++) {                // M0 = A^32
                double q0 = M[0] * M[0] + M[1] * M[2], q1 = M[0] * M[1] + M[1] * M[3];
                double q2 = M[2] * M[0] + M[3] * M[2], q3 = M[2] * M[1] + M[3] * M[3];
                M[0] = q0; M[1] = q1; M[2] = q2; M[3] = q3;
            }
            for (int k = 0; k < 7; k++) {                // lv[k] = M0^(2^k)
                for (int j = 0; j < 4; j++) L.lv[k][n][j] = (float)M[j];
                double q0 = M[0] * M[0] + M[1] * M[2], q1 = M[0] * M[1] + M[1] * M[3];
                double q2 = M[2] * M[0] + M[3] * M[2], q3 = M[2] * M[1] + M[3] * M[3];
                M[0] = q0; M[1] = q1; M[2] = q2; M[3] = q3;
            }
            n++;
        }
    }
    C.c0 = (float)c0.real();
}

extern "C" void kernel_launch(void* const* d_in, const int* in_sizes, int n_in,
                              void* d_out, int out_size, void* d_ws, size_t ws_size,
                              hipStream_t stream) {
    const float* audio = (const float*)d_in[0];
    float* out = (float*)d_out;

    CoeffsS C; LvS L;
    compute_coeffs(C, L);

    // ws: ybuf 33.8MB + mt 8KB + aggA/aggB/xpreA/xpreB 264KB each
    char* ws = (char*)d_ws;
    size_t o = 0;
    auto alloc = [&](size_t bytes) { size_t r = o; o += (bytes + 255) & ~(size_t)255; return r; };
    float*  ybuf  = (float*)(ws + alloc((size_t)NB * LPAD * sizeof(float)));
    float4* mt    = (float4*)(ws + alloc(512 * sizeof(float4)));
    float2* aggA  = (float2*)(ws + alloc((size_t)NB * NT * NP * sizeof(float2)));
    float2* aggB  = (float2*)(ws + alloc((size_t)NB * NT * NP * sizeof(float2)));
    float2* xpreA = (float2*)(ws + alloc((size_t)NB * NT * NP * sizeof(float2)));
    float2* xpreB = (float2*)(ws + alloc((size_t)NB * NT * NP * sizeof(float2)));

    dim3 blk(256), g(NBX, NB);

    k_init     <<<2,  256, 0, stream>>>(mt, L);
    k_aggA     <<<g,  blk, 0, stream>>>(audio, aggA, C, L);
    k_prefix<0><<<NB, 64,  0, stream>>>(aggA, xpreA, ybuf, C, L);
    k_full<0>  <<<g,  blk, 0, stream>>>(audio, ybuf, xpreA, aggB, mt, C, L);
    k_prefix<1><<<NB, 64,  0, stream>>>(aggB, xpreB, ybuf, C, L);
    k_full<1>  <<<g,  blk, 0, stream>>>(ybuf, out, xpreB, nullptr, mt, C, L);
}

// Round 12
// 140.343 us; speedup vs baseline: 1.0041x; 1.0041x over previous
//
#include <hip/hip_runtime.h>
#include <cmath>
#include <complex>

// sr=16000, band 500-7000, order 8 -> 16 poles = 8 real 2nd-order sections.
#define NB    32
#define LX    262144
#define PAD   51                      // padlen = 3*17
#define LTOT  (LX + 2 * PAD)          // 262246
#define CM    16                      // samples per chunk (= per thread)
#define F_PAD 3994                    // zero-input front pad
#define LPAD  (LTOT + F_PAD)          // 266240 = 65 * 4096 (tile-aligned)
#define CPB   256                     // chunks (threads) per tile
#define TILE  (CPB * CM)              // 4096 samples per tile
#define NTILE (LPAD / TILE)           // 65 tiles per row
#define WTS   (64 * CM)               // 1024 samples per wave-tile
#define NTW   (LPAD / WTS)            // 260 wave-tiles per row
#define NP    8
#define LDSR  18                      // floats per LDS lane-row (even: f2-aligned)

struct CoeffsS { float a1[NP], a2[NP], b0[NP], b1[NP], g1a[NP], g1b[NP], c0; };
// lv[k][q] = (A_q^CM)^(2^k) = M0^(2^k); lv[6] = M0^64 = wave-tile transition
struct LvS { float lv[9][NP][4]; };

// ---------------------------------------------------------------------------
// init: build mt[t*8+q] = M0^t (t=0..255) via binary exponentiation.
__global__ void k_init(float4* __restrict__ mt, LvS L) {
    int id = blockIdx.x * 256 + threadIdx.x;          // 0..2047
    int t = id >> 3, q = id & 7;
    float m0 = 1.f, m1 = 0.f, m2 = 0.f, m3 = 1.f;
    for (int k = 0; k < 8; k++)
        if ((t >> k) & 1) {
            float a0 = L.lv[k][q][0], a1 = L.lv[k][q][1];
            float a2 = L.lv[k][q][2], a3 = L.lv[k][q][3];
            float n0 = a0 * m0 + a1 * m2, n1 = a0 * m1 + a1 * m3;
            float n2 = a2 * m0 + a3 * m2, n3 = a2 * m1 + a3 * m3;
            m0 = n0; m1 = n1; m2 = n2; m3 = n3;
        }
    mt[id] = make_float4(m0, m1, m2, m3);
}

// ---------------------------------------------------------------------------
// u-loader pass A: chunk c covers t' = c*CM..+CM, real t = t' - F_PAD.
__device__ __forceinline__ void load_uA(const float* __restrict__ x,
                                        float base, int c, float (&u)[CM]) {
    int t0 = c * CM - F_PAD;
    if (t0 >= PAD && t0 + CM <= PAD + LX) {
        const float* xs = x + (t0 - PAD);
#pragma unroll
        for (int m = 0; m < CM / 4; m++) {
            float4 v = *reinterpret_cast<const float4*>(xs + 4 * m);
            u[4 * m] = v.x - base; u[4 * m + 1] = v.y - base;
            u[4 * m + 2] = v.z - base; u[4 * m + 3] = v.w - base;
        }
    } else {
#pragma unroll
        for (int i = 0; i < CM; i++) {
            int t = t0 + i;
            float uu;
            if (t < 0) uu = 0.f;                        // front pad
            else {
                float e;
                if (t < PAD)            e = 2.0f * x[0] - x[PAD - t];
                else if (t < PAD + LX)  e = x[t - PAD];
                else                    e = 2.0f * x[LX - 1] - x[2 * LX + PAD - 2 - t];
                uu = e - base;
            }
            u[i] = uu;
        }
    }
}

// local chunk recurrence from zero state
__device__ __forceinline__ void local_states(const float (&u)[CM], const CoeffsS& C,
                                             float (&w1)[NP], float (&w2)[NP]) {
#pragma unroll
    for (int q = 0; q < NP; q++) { w1[q] = 0.f; w2[q] = 0.f; }
#pragma unroll
    for (int i = 0; i < CM; i++) {
        float uu = u[i];
#pragma unroll
        for (int q = 0; q < NP; q++) {
            float wt = fmaf(C.a1[q], w1[q], fmaf(C.a2[q], w2[q], uu));
            w2[q] = w1[q]; w1[q] = wt;
        }
    }
}

// block-level Hillis-Steele inclusive affine scan over 256 chunk states
__device__ __forceinline__ void block_scan(float2* sc2, int pos, const LvS& L,
                                           float (&w1)[NP], float (&w2)[NP]) {
#pragma unroll
    for (int q = 0; q < NP; q++) sc2[q * 256 + pos] = make_float2(w1[q], w2[q]);
    __syncthreads();
#pragma unroll
    for (int k = 0; k < 8; k++) {
        int d = 1 << k;
        float2 o[NP];
        if (pos >= d) {
#pragma unroll
            for (int q = 0; q < NP; q++) o[q] = sc2[q * 256 + pos - d];
        }
        __syncthreads();
        if (pos >= d) {
#pragma unroll
            for (int q = 0; q < NP; q++) {
                w1[q] = fmaf(L.lv[k][q][0], o[q].x, fmaf(L.lv[k][q][1], o[q].y, w1[q]));
                w2[q] = fmaf(L.lv[k][q][2], o[q].x, fmaf(L.lv[k][q][3], o[q].y, w2[q]));
            }
        }
#pragma unroll
        for (int q = 0; q < NP; q++) sc2[q * 256 + pos] = make_float2(w1[q], w2[q]);
        __syncthreads();
    }
}

// wave directional reduce, FORWARD order (lane 0 first): lane 63 gets
// agg = f63 + M0 f62 + ... + M0^63 f0.  lv[k] = M0^(2^k).
__device__ __forceinline__ void wave_reduce_fwd(int l, const LvS& L,
                                                float (&w1)[NP], float (&w2)[NP]) {
#pragma unroll
    for (int k = 0; k < 6; k++) {
        int d = 1 << k;
#pragma unroll
        for (int q = 0; q < NP; q++) {
            float o1 = __shfl_up(w1[q], d);
            float o2 = __shfl_up(w2[q], d);
            if (l >= d) {
                w1[q] = fmaf(L.lv[k][q][0], o1, fmaf(L.lv[k][q][1], o2, w1[q]));
                w2[q] = fmaf(L.lv[k][q][2], o1, fmaf(L.lv[k][q][3], o2, w2[q]));
            }
        }
    }
}

// wave directional reduce, REVERSE order (lane 63 first): lane 0 gets
// agg = f0 + M0 f1 + ... + M0^63 f63.
__device__ __forceinline__ void wave_reduce_rev(int l, const LvS& L,
                                                float (&w1)[NP], float (&w2)[NP]) {
#pragma unroll
    for (int k = 0; k < 6; k++) {
        int d = 1 << k;
#pragma unroll
        for (int q = 0; q < NP; q++) {
            float o1 = __shfl_down(w1[q], d);
            float o2 = __shfl_down(w2[q], d);
            if (l + d <= 63) {
                w1[q] = fmaf(L.lv[k][q][0], o1, fmaf(L.lv[k][q][1], o2, w1[q]));
                w2[q] = fmaf(L.lv[k][q][2], o1, fmaf(L.lv[k][q][3], o2, w2[q]));
            }
        }
    }
}

// ---------------------------------------------------------------------------
// K1 (pass A): per-WAVE-tile aggregates from zero init. No LDS, no barriers.
__global__ __launch_bounds__(256) void k_agg(const float* __restrict__ audio,
                                             float2* __restrict__ agg,
                                             CoeffsS C, LvS L) {
    int tid = threadIdx.x, tx = blockIdx.x, b = blockIdx.y;
    int wv = tid >> 6, l = tid & 63;
    int wt = tx * 4 + wv;                 // wave-tile index 0..NTW-1
    const float* x = audio + (size_t)b * LX;
    float base = 2.0f * x[0] - x[PAD];
    float u[CM];
    load_uA(x, base, tx * CPB + tid, u);
    float w1[NP], w2[NP];
    local_states(u, C, w1, w2);
    wave_reduce_fwd(l, L, w1, w2);
    if (l == 63) {
#pragma unroll
        for (int q = 0; q < NP; q++)
            agg[(size_t)(b * NTW + wt) * NP + q] = make_float2(w1[q], w2[q]);
    }
}

// ---------------------------------------------------------------------------
// K2: per-row walk over NTW wave aggregates (LDS-preloaded) -> tile entry X.
// CORR=1 (pass B): subtract base*g1024 pair from each raw aggregate.
template <int CORR>
__global__ __launch_bounds__(256) void k_prefix(const float2* __restrict__ agg,
                                                float2* __restrict__ xpre,
                                                const float* __restrict__ ybuf,
                                                CoeffsS C, LvS L) {
    __shared__ float2 sa[NTW * NP];       // 16.6 KB
    int b = blockIdx.x, tid = threadIdx.x;
    const float2* ab = agg + (size_t)b * NTW * NP;
    for (int id = tid; id < NTW * NP; id += 256) sa[id] = ab[id];
    __syncthreads();
    if (tid < NP) {
        int q = tid;
        float B0 = L.lv[6][q][0], B1 = L.lv[6][q][1];   // M0^64 = A^1024
        float B2 = L.lv[6][q][2], B3 = L.lv[6][q][3];
        float cga = 0.f, cgb = 0.f;
        if (CORR) {
            float base = ybuf[(size_t)b * LPAD];
            cga = base * C.g1a[q]; cgb = base * C.g1b[q];
        }
        float X1 = 0.f, X2 = 0.f;
        for (int t = 0; t < NTW; t++) {
            if ((t & 3) == 0)
                xpre[(size_t)(b * NTILE + (t >> 2)) * NP + q] = make_float2(X1, X2);
            float2 f = sa[t * NP + q];
            float n1 = fmaf(B0, X1, fmaf(B1, X2, f.x - cga));
            float n2 = fmaf(B2, X1, fmaf(B3, X2, f.y - cgb));
            X1 = n1; X2 = n2;
        }
    }
}

// ---------------------------------------------------------------------------
// K3: local scan; entry from precomputed X; replay; coalesced store.
// PASS 0: in=audio -> ybuf reversed; also emits raw pass-B WAVE aggregates
//         via in-register reverse recurrence + shfl reduce (no extra scan).
// PASS 1: in=ybuf -> final out (un-reverse + trim PAD).
template <int PASS>
__global__ __launch_bounds__(256) void k_full(const float* __restrict__ in,
                                              float* __restrict__ outp,
                                              const float2* __restrict__ xpre,
                                              float2* __restrict__ aggB,
                                              const float4* __restrict__ mt,
                                              CoeffsS C, LvS L) {
    __shared__ __align__(16) float lds[CPB * LDSR];   // 18432 B (aliases sc2)
    __shared__ float2 xb[NP];
    float2* sc2 = reinterpret_cast<float2*>(lds);     // 16 KB scan region
    int tid = threadIdx.x, tx = blockIdx.x, b = blockIdx.y;
    int c = tx * CPB + tid;

    // ---- load u ----
    float u[CM];
    if (PASS == 0) {
        const float* x = in + (size_t)b * LX;
        float base = 2.0f * x[0] - x[PAD];
        load_uA(x, base, c, u);
    } else {
        const float* yb = in + (size_t)b * LPAD;
        float base = yb[0];               // = y[LTOT-1]
        const float* ys = yb + (size_t)c * CM;
#pragma unroll
        for (int m = 0; m < CM / 4; m++) {
            float4 v = *reinterpret_cast<const float4*>(ys + 4 * m);
            u[4 * m] = v.x - base; u[4 * m + 1] = v.y - base;
            u[4 * m + 2] = v.z - base; u[4 * m + 3] = v.w - base;
        }
    }

    // tile entry X (precomputed) -> LDS (visible after scan's first barrier)
    if (tid < NP) xb[tid] = xpre[(size_t)(b * NTILE + tx) * NP + tid];

    // ---- local states + block scan ----
    float w1[NP], w2[NP];
    local_states(u, C, w1, w2);
    block_scan(sc2, tid, L, w1, w2);
    float e1[NP], e2[NP];                 // exclusive local prefix
#pragma unroll
    for (int q = 0; q < NP; q++) {
        float2 ev = (tid > 0) ? sc2[q * 256 + tid - 1] : make_float2(0.f, 0.f);
        e1[q] = ev.x; e2[q] = ev.y;
    }

    // ---- entry = E + M0^tid * X; replay u -> y (registers) ----
#pragma unroll
    for (int q = 0; q < NP; q++) {
        float4 m4 = mt[tid * NP + q];
        float2 X = xb[q];
        w1[q] = fmaf(m4.x, X.x, fmaf(m4.y, X.y, e1[q]));
        w2[q] = fmaf(m4.z, X.x, fmaf(m4.w, X.y, e2[q]));
    }
#pragma unroll
    for (int i = 0; i < CM; i++) {
        float uu = u[i];
        float y = C.c0 * uu;
#pragma unroll
        for (int q = 0; q < NP; q++) {
            float wt = fmaf(C.a1[q], w1[q], fmaf(C.a2[q], w2[q], uu));
            y = fmaf(C.b0[q], wt, fmaf(C.b1[q], w1[q], y));
            w2[q] = w1[q]; w1[q] = wt;
        }
        u[i] = y;                          // u now holds y
    }

    if (PASS == 0) {
        // ---- fused raw pass-B wave aggregates (registers + shfl only) ----
        int wv = tid >> 6, l = tid & 63;
        float t1[NP], t2[NP];
#pragma unroll
        for (int q = 0; q < NP; q++) { t1[q] = 0.f; t2[q] = 0.f; }
#pragma unroll
        for (int i = CM - 1; i >= 0; --i) {   // pass-B order within chunk
            float wvv = u[i];
#pragma unroll
            for (int q = 0; q < NP; q++) {
                float wt = fmaf(C.a1[q], t1[q], fmaf(C.a2[q], t2[q], wvv));
                t2[q] = t1[q]; t1[q] = wt;
            }
        }
        wave_reduce_rev(l, L, t1, t2);
        if (l == 0) {
            int kB = NTW - 1 - (tx * 4 + wv);  // pass-B wave-tile index
#pragma unroll
            for (int q = 0; q < NP; q++)
                aggB[(size_t)(b * NTW + kB) * NP + q] = make_float2(t1[q], t2[q]);
        }
    }

    // ---- stage y to LDS (after all sc2 reads are done) ----
    __syncthreads();
    if (PASS == 0) {
#pragma unroll
        for (int k = 0; k < CM / 2; k++)
            *reinterpret_cast<float2*>(&lds[tid * LDSR + 2 * k]) =
                make_float2(u[2 * k], u[2 * k + 1]);
    } else {
#pragma unroll
        for (int i = 0; i < CM; i++) lds[tid * LDSR + i] = u[i];
    }
    __syncthreads();

    if (PASS == 0) {
        // coalesced REVERSED store: ybuf[k] = y[LPAD-1-t']
        float4* yb4 = reinterpret_cast<float4*>(
            outp + (size_t)b * LPAD + (size_t)(NTILE - 1 - tx) * TILE);
#pragma unroll
        for (int m = 0; m < 4; m++) {
            int o4 = m * CPB + tid;            // 0..1023
            int ts = 255 - (o4 >> 2);
            int ih = 15 - 4 * (o4 & 3);
            float2 a  = *reinterpret_cast<const float2*>(&lds[ts * LDSR + ih - 1]);
            float2 b2 = *reinterpret_cast<const float2*>(&lds[ts * LDSR + ih - 3]);
            yb4[o4] = make_float4(a.y, a.x, b2.y, b2.x);
        }
    } else {
        // out[j] = y2[s], j = (LTOT-1-PAD) - s  (un-reverse + trim PAD)
        float* ob = outp + (size_t)b * LX;
        int J0 = (LTOT - 1 - PAD) - tx * TILE;
#pragma unroll
        for (int m = 0; m < CM; m++) {
            int o = m * CPB + tid;
            int j = J0 - o;
            if (j >= 0 && j < LX)
                ob[j] = lds[(o >> 4) * LDSR + (o & 15)];
        }
    }
}

// ---------------------------------------------------------------------------
// Host: scipy butter(8,[500,7000]/8000,'bandpass') -> real 2nd-order sections
// + chunk-transition (A^16) power levels + exact 1024-step const-input pair.
static void compute_coeffs(CoeffsS& C, LvS& L) {
    using cd = std::complex<double>;
    const int N = 8;
    const double sr = 16000.0, lo = 500.0, hi = 7000.0, fs = 2.0;
    double w0 = 2.0 * fs * std::tan(M_PI * (2.0 * lo / sr) / fs);
    double w1 = 2.0 * fs * std::tan(M_PI * (2.0 * hi / sr) / fs);
    double bw = w1 - w0, wo = std::sqrt(w0 * w1);
    cd pbp[16];
    for (int k = 0; k < N; k++) {
        int m = -N + 1 + 2 * k;
        cd pl = -std::exp(cd(0.0, M_PI * m / (2.0 * N)));
        pl *= bw / 2.0;
        cd s = std::sqrt(pl * pl - cd(wo * wo, 0.0));
        pbp[k] = pl + s; pbp[k + N] = pl - s;
    }
    double kbp = std::pow(bw, (double)N);
    const double fs2 = 4.0;
    cd pd[16], denom = 1.0;
    for (int i = 0; i < 16; i++) {
        pd[i] = (cd(fs2, 0.0) + pbp[i]) / (cd(fs2, 0.0) - pbp[i]);
        denom *= (cd(fs2, 0.0) - pbp[i]);
    }
    double kd = kbp * std::real(cd(std::pow(fs2, 8.0), 0.0) / denom);
    cd prodp = 1.0;
    for (int i = 0; i < 16; i++) prodp *= pd[i];
    cd c0 = cd(kd, 0.0) / prodp;
    int n = 0;
    for (int i = 0; i < 16; i++) {
        if (pd[i].imag() <= 0.0) continue;
        cd inv = 1.0 / pd[i];
        cd t1 = cd(1.0, 0.0) - inv, t2 = cd(1.0, 0.0) + inv;
        cd numr = cd(kd, 0.0);
        for (int k = 0; k < 8; k++) numr *= t1;
        for (int k = 0; k < 8; k++) numr *= t2;
        cd den = 1.0;
        for (int j = 0; j < 16; j++)
            if (j != i) den *= (cd(1.0, 0.0) - pd[j] * inv);
        cd r2 = 2.0 * numr / den;             // conjugate pair folded
        if (n < NP) {
            double a1 = 2.0 * pd[i].real();
            double a2 = -std::norm(pd[i]);
            C.a1[n] = (float)a1; C.a2[n] = (float)a2;
            C.b0[n] = (float)r2.real();
            C.b1[n] = (float)(-(r2.real() * pd[i].real() + r2.imag() * pd[i].imag()));
            // exact 1024-step constant-input response pair (for corr in prefixB)
            double gw1 = 0.0, gw2 = 0.0;
            for (int k = 0; k < 1024; k++) {
                double gt = a1 * gw1 + a2 * gw2 + 1.0; gw2 = gw1; gw1 = gt;
            }
            C.g1a[n] = (float)gw1; C.g1b[n] = (float)gw2;
            double M[4] = { a1, a2, 1.0, 0.0 };       // A = [[a1,a2],[1,0]]
            for (int s = 0; s < 4; s++) {             // M0 = A^16
                double q0 = M[0] * M[0] + M[1] * M[2], q1 = M[0] * M[1] + M[1] * M[3];
                double q2 = M[2] * M[0] + M[3] * M[2], q3 = M[2] * M[1] + M[3] * M[3];
                M[0] = q0; M[1] = q1; M[2] = q2; M[3] = q3;
            }
            for (int k = 0; k < 9; k++) {             // lv[k] = M0^(2^k)
                for (int j = 0; j < 4; j++) L.lv[k][n][j] = (float)M[j];
                double q0 = M[0] * M[0] + M[1] * M[2], q1 = M[0] * M[1] + M[1] * M[3];
                double q2 = M[2] * M[0] + M[3] * M[2], q3 = M[2] * M[1] + M[3] * M[3];
                M[0] = q0; M[1] = q1; M[2] = q2; M[3] = q3;
            }
            n++;
        }
    }
    C.c0 = (float)c0.real();
}

extern "C" void kernel_launch(void* const* d_in, const int* in_sizes, int n_in,
                              void* d_out, int out_size, void* d_ws, size_t ws_size,
                              hipStream_t stream) {
    const float* audio = (const float*)d_in[0];
    float* out = (float*)d_out;

    CoeffsS C; LvS L;
    compute_coeffs(C, L);

    // ws: ybuf 34.1MB + mt 32KB + aggA/aggB 532KB + xpreA/xpreB 133KB each
    char* ws = (char*)d_ws;
    size_t o = 0;
    auto alloc = [&](size_t bytes) { size_t r = o; o += (bytes + 255) & ~(size_t)255; return r; };
    float*  ybuf  = (float*)(ws + alloc((size_t)NB * LPAD * sizeof(float)));
    float4* mt    = (float4*)(ws + alloc(2048 * sizeof(float4)));
    float2* aggA  = (float2*)(ws + alloc((size_t)NB * NTW * NP * sizeof(float2)));
    float2* aggB  = (float2*)(ws + alloc((size_t)NB * NTW * NP * sizeof(float2)));
    float2* xpreA = (float2*)(ws + alloc((size_t)NB * NTILE * NP * sizeof(float2)));
    float2* xpreB = (float2*)(ws + alloc((size_t)NB * NTILE * NP * sizeof(float2)));

    dim3 blk(256), g(NTILE, NB);

    k_init     <<<8,  256, 0, stream>>>(mt, L);
    k_agg      <<<g,  blk, 0, stream>>>(audio, aggA, C, L);
    k_prefix<0><<<NB, blk, 0, stream>>>(aggA, xpreA, ybuf, C, L);
    k_full<0>  <<<g,  blk, 0, stream>>>(audio, ybuf, xpreA, aggB, mt, C, L);
    k_prefix<1><<<NB, blk, 0, stream>>>(aggB, xpreB, ybuf, C, L);
    k_full<1>  <<<g,  blk, 0, stream>>>(ybuf, out, xpreB, nullptr, mt, C, L);
}

// Round 13
// 140.168 us; speedup vs baseline: 1.0053x; 1.0012x over previous
//
#include <hip/hip_runtime.h>
#include <cmath>
#include <complex>

// sr=16000, band 500-7000, order 8 -> 16 poles = 8 real 2nd-order sections.
#define NB    32
#define LX    262144
#define PAD   51                      // padlen = 3*17
#define LTOT  (LX + 2 * PAD)          // 262246
#define CM    32                      // samples per chunk (= per thread)
#define F_PAD 8090                    // zero-input front pad
#define LPAD  (LTOT + F_PAD)          // 270336 = 33 * 8192 (tile-aligned)
#define CPB   256                     // threads per block
#define TILE  (CPB * CM)              // 8192 samples per block-tile
#define NTILE (LPAD / TILE)           // 33 block-tiles per row
#define WTS   (64 * CM)               // 2048 samples per wave-tile
#define NTW   (LPAD / WTS)            // 132 wave-tiles per row
#define NP    8
#define LDSR  34                      // floats per LDS lane-row (proven: low conflict)

struct CoeffsS { float a1[NP], a2[NP], b0[NP], b1[NP], g1a[NP], g1b[NP], c0; };
// lv[k][q] = (A_q^CM)^(2^k) = M0^(2^k); lv[6] = M0^64 = wave-tile transition
struct LvS { float lv[9][NP][4]; };

// ---------------------------------------------------------------------------
// init: build mt[t*8+q] = M0^t (t=0..255) via binary exponentiation.
__global__ void k_init(float4* __restrict__ mt, LvS L) {
    int id = blockIdx.x * 256 + threadIdx.x;          // 0..2047
    int t = id >> 3, q = id & 7;
    float m0 = 1.f, m1 = 0.f, m2 = 0.f, m3 = 1.f;
    for (int k = 0; k < 8; k++)
        if ((t >> k) & 1) {
            float a0 = L.lv[k][q][0], a1 = L.lv[k][q][1];
            float a2 = L.lv[k][q][2], a3 = L.lv[k][q][3];
            float n0 = a0 * m0 + a1 * m2, n1 = a0 * m1 + a1 * m3;
            float n2 = a2 * m0 + a3 * m2, n3 = a2 * m1 + a3 * m3;
            m0 = n0; m1 = n1; m2 = n2; m3 = n3;
        }
    mt[id] = make_float4(m0, m1, m2, m3);
}

// ---------------------------------------------------------------------------
// u-loader pass A: chunk c covers t' = c*CM..+CM, real t = t' - F_PAD.
__device__ __forceinline__ void load_uA(const float* __restrict__ x,
                                        float base, int c, float (&u)[CM]) {
    int t0 = c * CM - F_PAD;
    if (t0 >= PAD && t0 + CM <= PAD + LX) {
        const float* xs = x + (t0 - PAD);
#pragma unroll
        for (int m = 0; m < CM / 4; m++) {
            float4 v = *reinterpret_cast<const float4*>(xs + 4 * m);
            u[4 * m] = v.x - base; u[4 * m + 1] = v.y - base;
            u[4 * m + 2] = v.z - base; u[4 * m + 3] = v.w - base;
        }
    } else {
#pragma unroll
        for (int i = 0; i < CM; i++) {
            int t = t0 + i;
            float uu;
            if (t < 0) uu = 0.f;                        // front pad
            else {
                float e;
                if (t < PAD)            e = 2.0f * x[0] - x[PAD - t];
                else if (t < PAD + LX)  e = x[t - PAD];
                else                    e = 2.0f * x[LX - 1] - x[2 * LX + PAD - 2 - t];
                uu = e - base;
            }
            u[i] = uu;
        }
    }
}

// local chunk recurrence from zero state
__device__ __forceinline__ void local_states(const float (&u)[CM], const CoeffsS& C,
                                             float (&w1)[NP], float (&w2)[NP]) {
#pragma unroll
    for (int q = 0; q < NP; q++) { w1[q] = 0.f; w2[q] = 0.f; }
#pragma unroll
    for (int i = 0; i < CM; i++) {
        float uu = u[i];
#pragma unroll
        for (int q = 0; q < NP; q++) {
            float wt = fmaf(C.a1[q], w1[q], fmaf(C.a2[q], w2[q], uu));
            w2[q] = w1[q]; w1[q] = wt;
        }
    }
}

// wave inclusive affine scan, FORWARD (lane 0 first): lane l gets
// W_l = f_l + M0 f_{l-1} + ... + M0^l f_0.  lv[k] = M0^(2^k). No barriers.
__device__ __forceinline__ void wave_scan_fwd(int l, const LvS& L,
                                              float (&w1)[NP], float (&w2)[NP]) {
#pragma unroll
    for (int k = 0; k < 6; k++) {
        int d = 1 << k;
#pragma unroll
        for (int q = 0; q < NP; q++) {
            float o1 = __shfl_up(w1[q], d);
            float o2 = __shfl_up(w2[q], d);
            if (l >= d) {
                w1[q] = fmaf(L.lv[k][q][0], o1, fmaf(L.lv[k][q][1], o2, w1[q]));
                w2[q] = fmaf(L.lv[k][q][2], o1, fmaf(L.lv[k][q][3], o2, w2[q]));
            }
        }
    }
}

// wave reduce, REVERSE order (lane 63 first): lane 0 gets
// G = f_0 + M0 f_1 + ... + M0^63 f_63.
__device__ __forceinline__ void wave_reduce_rev(int l, const LvS& L,
                                                float (&w1)[NP], float (&w2)[NP]) {
#pragma unroll
    for (int k = 0; k < 6; k++) {
        int d = 1 << k;
#pragma unroll
        for (int q = 0; q < NP; q++) {
            float o1 = __shfl_down(w1[q], d);
            float o2 = __shfl_down(w2[q], d);
            if (l + d <= 63) {
                w1[q] = fmaf(L.lv[k][q][0], o1, fmaf(L.lv[k][q][1], o2, w1[q]));
                w2[q] = fmaf(L.lv[k][q][2], o1, fmaf(L.lv[k][q][3], o2, w2[q]));
            }
        }
    }
}

// ---------------------------------------------------------------------------
// K1 (pass A): per-WAVE-tile aggregates from zero init. No LDS, no barriers.
__global__ __launch_bounds__(256, 4) void k_agg(const float* __restrict__ audio,
                                                float2* __restrict__ agg,
                                                CoeffsS C, LvS L) {
    int tid = threadIdx.x, tx = blockIdx.x, b = blockIdx.y;
    int wv = tid >> 6, l = tid & 63;
    int wt = tx * 4 + wv;
    const float* x = audio + (size_t)b * LX;
    float base = 2.0f * x[0] - x[PAD];
    float u[CM];
    load_uA(x, base, tx * CPB + tid, u);
    float w1[NP], w2[NP];
    local_states(u, C, w1, w2);
    wave_scan_fwd(l, L, w1, w2);
    if (l == 63) {
#pragma unroll
        for (int q = 0; q < NP; q++)
            agg[(size_t)(b * NTW + wt) * NP + q] = make_float2(w1[q], w2[q]);
    }
}

// ---------------------------------------------------------------------------
// K2: per-row serial walk over NTW wave aggregates (LDS-staged) -> exclusive
// per-wave entry states X. CORR=1 (pass B): subtract base*g2048 per aggregate.
template <int CORR>
__global__ __launch_bounds__(256) void k_prefix(const float2* __restrict__ agg,
                                                float2* __restrict__ xpre,
                                                const float* __restrict__ ybuf,
                                                CoeffsS C, LvS L) {
    __shared__ float2 sa[NTW * NP];       // 8448 B
    int b = blockIdx.x, tid = threadIdx.x;
    const float2* ab = agg + (size_t)b * NTW * NP;
    for (int id = tid; id < NTW * NP; id += 256) sa[id] = ab[id];
    __syncthreads();
    if (tid < NP) {
        int q = tid;
        float B0 = L.lv[6][q][0], B1 = L.lv[6][q][1];   // M0^64 = A^2048
        float B2 = L.lv[6][q][2], B3 = L.lv[6][q][3];
        float cga = 0.f, cgb = 0.f;
        if (CORR) {
            float base = ybuf[(size_t)b * LPAD];
            cga = base * C.g1a[q]; cgb = base * C.g1b[q];
        }
        float X1 = 0.f, X2 = 0.f;
        for (int t = 0; t < NTW; t++) {
            xpre[(size_t)(b * NTW + t) * NP + q] = make_float2(X1, X2);
            float2 f = sa[t * NP + q];
            float n1 = fmaf(B0, X1, fmaf(B1, X2, f.x - cga));
            float n2 = fmaf(B2, X1, fmaf(B3, X2, f.y - cgb));
            X1 = n1; X2 = n2;
        }
    }
}

// ---------------------------------------------------------------------------
// K3: wave scan (no barriers); entry from precomputed per-wave X; replay;
// block-staged coalesced store (1 barrier).
// PASS 0: in=audio -> ybuf reversed; also emits raw pass-B wave aggregates.
// PASS 1: in=ybuf -> final out (un-reverse + trim PAD).
template <int PASS>
__global__ __launch_bounds__(256, 4) void k_full(const float* __restrict__ in,
                                                 float* __restrict__ outp,
                                                 const float2* __restrict__ xpre,
                                                 float2* __restrict__ aggB,
                                                 const float4* __restrict__ mt,
                                                 CoeffsS C, LvS L) {
    __shared__ __align__(16) float lds[CPB * LDSR];   // 34816 B
    int tid = threadIdx.x, tx = blockIdx.x, b = blockIdx.y;
    int wv = tid >> 6, l = tid & 63;
    int wt = tx * 4 + wv;
    int c = tx * CPB + tid;

    // ---- load u ----
    float u[CM];
    if (PASS == 0) {
        const float* x = in + (size_t)b * LX;
        float base = 2.0f * x[0] - x[PAD];
        load_uA(x, base, c, u);
    } else {
        const float* yb = in + (size_t)b * LPAD;
        float base = yb[0];               // = y[LTOT-1]
        const float* ys = yb + (size_t)c * CM;
#pragma unroll
        for (int m = 0; m < CM / 4; m++) {
            float4 v = *reinterpret_cast<const float4*>(ys + 4 * m);
            u[4 * m] = v.x - base; u[4 * m + 1] = v.y - base;
            u[4 * m + 2] = v.z - base; u[4 * m + 3] = v.w - base;
        }
    }

    // ---- local states + wave scan (registers, no barriers) ----
    float w1[NP], w2[NP];
    local_states(u, C, w1, w2);
    wave_scan_fwd(l, L, w1, w2);

    // ---- entry = (exclusive within wave) + M0^l * X_wave; replay ----
#pragma unroll
    for (int q = 0; q < NP; q++) {
        float a = __shfl_up(w1[q], 1), bb = __shfl_up(w2[q], 1);
        float e1 = (l == 0) ? 0.f : a;
        float e2 = (l == 0) ? 0.f : bb;
        float2 X = xpre[(size_t)(b * NTW + wt) * NP + q];
        float4 m4 = mt[l * NP + q];
        w1[q] = fmaf(m4.x, X.x, fmaf(m4.y, X.y, e1));
        w2[q] = fmaf(m4.z, X.x, fmaf(m4.w, X.y, e2));
    }
#pragma unroll
    for (int i = 0; i < CM; i++) {
        float uu = u[i];
        float y = C.c0 * uu;
#pragma unroll
        for (int q = 0; q < NP; q++) {
            float wt2 = fmaf(C.a1[q], w1[q], fmaf(C.a2[q], w2[q], uu));
            y = fmaf(C.b0[q], wt2, fmaf(C.b1[q], w1[q], y));
            w2[q] = w1[q]; w1[q] = wt2;
        }
        u[i] = y;                          // u now holds y
    }

    if (PASS == 0) {
        // ---- fused raw pass-B wave aggregates (registers + shfl only) ----
        float t1[NP], t2[NP];
#pragma unroll
        for (int q = 0; q < NP; q++) { t1[q] = 0.f; t2[q] = 0.f; }
#pragma unroll
        for (int i = CM - 1; i >= 0; --i) {   // pass-B order within chunk
            float wvv = u[i];
#pragma unroll
            for (int q = 0; q < NP; q++) {
                float wt2 = fmaf(C.a1[q], t1[q], fmaf(C.a2[q], t2[q], wvv));
                t2[q] = t1[q]; t1[q] = wt2;
            }
        }
        wave_reduce_rev(l, L, t1, t2);
        if (l == 0) {
            int kB = NTW - 1 - wt;            // pass-B wave-tile index
#pragma unroll
            for (int q = 0; q < NP; q++)
                aggB[(size_t)(b * NTW + kB) * NP + q] = make_float2(t1[q], t2[q]);
        }
    }

    // ---- stage y to LDS; barrier; coalesced store (round-10-proven) ----
    if (PASS == 0) {
#pragma unroll
        for (int k = 0; k < CM / 2; k++)
            *reinterpret_cast<float2*>(&lds[tid * LDSR + 2 * k]) =
                make_float2(u[2 * k], u[2 * k + 1]);
    } else {
#pragma unroll
        for (int i = 0; i < CM; i++) lds[tid * LDSR + i] = u[i];
    }
    __syncthreads();

    if (PASS == 0) {
        // coalesced REVERSED store: ybuf[k] = y[LPAD-1-t']
        float4* yb4 = reinterpret_cast<float4*>(
            outp + (size_t)b * LPAD + (size_t)(NTILE - 1 - tx) * TILE);
#pragma unroll
        for (int m = 0; m < 8; m++) {
            int o4 = m * CPB + tid;            // 0..2047
            int ts = 255 - (o4 >> 3);
            int ih = 31 - 4 * (o4 & 7);
            float2 a  = *reinterpret_cast<const float2*>(&lds[ts * LDSR + ih - 1]);
            float2 b2 = *reinterpret_cast<const float2*>(&lds[ts * LDSR + ih - 3]);
            yb4[o4] = make_float4(a.y, a.x, b2.y, b2.x);
        }
    } else {
        // out[j] = y2[s], j = (LTOT-1-PAD) - s  (un-reverse + trim PAD)
        float* ob = outp + (size_t)b * LX;
        int J0 = (LTOT - 1 - PAD) - tx * TILE;
#pragma unroll
        for (int m = 0; m < CM; m++) {
            int o = m * CPB + tid;
            int j = J0 - o;
            if (j >= 0 && j < LX)
                ob[j] = lds[(o >> 5) * LDSR + (o & 31)];
        }
    }
}

// ---------------------------------------------------------------------------
// Host: scipy butter(8,[500,7000]/8000,'bandpass') -> real 2nd-order sections
// + chunk-transition (A^32) power levels + exact 2048-step const-input pair.
static void compute_coeffs(CoeffsS& C, LvS& L) {
    using cd = std::complex<double>;
    const int N = 8;
    const double sr = 16000.0, lo = 500.0, hi = 7000.0, fs = 2.0;
    double w0 = 2.0 * fs * std::tan(M_PI * (2.0 * lo / sr) / fs);
    double w1 = 2.0 * fs * std::tan(M_PI * (2.0 * hi / sr) / fs);
    double bw = w1 - w0, wo = std::sqrt(w0 * w1);
    cd pbp[16];
    for (int k = 0; k < N; k++) {
        int m = -N + 1 + 2 * k;
        cd pl = -std::exp(cd(0.0, M_PI * m / (2.0 * N)));
        pl *= bw / 2.0;
        cd s = std::sqrt(pl * pl - cd(wo * wo, 0.0));
        pbp[k] = pl + s; pbp[k + N] = pl - s;
    }
    double kbp = std::pow(bw, (double)N);
    const double fs2 = 4.0;
    cd pd[16], denom = 1.0;
    for (int i = 0; i < 16; i++) {
        pd[i] = (cd(fs2, 0.0) + pbp[i]) / (cd(fs2, 0.0) - pbp[i]);
        denom *= (cd(fs2, 0.0) - pbp[i]);
    }
    double kd = kbp * std::real(cd(std::pow(fs2, 8.0), 0.0) / denom);
    cd prodp = 1.0;
    for (int i = 0; i < 16; i++) prodp *= pd[i];
    cd c0 = cd(kd, 0.0) / prodp;
    int n = 0;
    for (int i = 0; i < 16; i++) {
        if (pd[i].imag() <= 0.0) continue;
        cd inv = 1.0 / pd[i];
        cd t1 = cd(1.0, 0.0) - inv, t2 = cd(1.0, 0.0) + inv;
        cd numr = cd(kd, 0.0);
        for (int k = 0; k < 8; k++) numr *= t1;
        for (int k = 0; k < 8; k++) numr *= t2;
        cd den = 1.0;
        for (int j = 0; j < 16; j++)
            if (j != i) den *= (cd(1.0, 0.0) - pd[j] * inv);
        cd r2 = 2.0 * numr / den;             // conjugate pair folded
        if (n < NP) {
            double a1 = 2.0 * pd[i].real();
            double a2 = -std::norm(pd[i]);
            C.a1[n] = (float)a1; C.a2[n] = (float)a2;
            C.b0[n] = (float)r2.real();
            C.b1[n] = (float)(-(r2.real() * pd[i].real() + r2.imag() * pd[i].imag()));
            // exact 2048-step constant-input response pair (prefixB correction)
            double gw1 = 0.0, gw2 = 0.0;
            for (int k = 0; k < 2048; k++) {
                double gt = a1 * gw1 + a2 * gw2 + 1.0; gw2 = gw1; gw1 = gt;
            }
            C.g1a[n] = (float)gw1; C.g1b[n] = (float)gw2;
            double M[4] = { a1, a2, 1.0, 0.0 };       // A = [[a1,a2],[1,0]]
            for (int s = 0; s < 5; s++) {             // M0 = A^32
                double q0 = M[0] * M[0] + M[1] * M[2], q1 = M[0] * M[1] + M[1] * M[3];
                double q2 = M[2] * M[0] + M[3] * M[2], q3 = M[2] * M[1] + M[3] * M[3];
                M[0] = q0; M[1] = q1; M[2] = q2; M[3] = q3;
            }
            for (int k = 0; k < 9; k++) {             // lv[k] = M0^(2^k)
                for (int j = 0; j < 4; j++) L.lv[k][n][j] = (float)M[j];
                double q0 = M[0] * M[0] + M[1] * M[2], q1 = M[0] * M[1] + M[1] * M[3];
                double q2 = M[2] * M[0] + M[3] * M[2], q3 = M[2] * M[1] + M[3] * M[3];
                M[0] = q0; M[1] = q1; M[2] = q2; M[3] = q3;
            }
            n++;
        }
    }
    C.c0 = (float)c0.real();
}

extern "C" void kernel_launch(void* const* d_in, const int* in_sizes, int n_in,
                              void* d_out, int out_size, void* d_ws, size_t ws_size,
                              hipStream_t stream) {
    const float* audio = (const float*)d_in[0];
    float* out = (float*)d_out;

    CoeffsS C; LvS L;
    compute_coeffs(C, L);

    // ws: ybuf 34.6MB + mt 32KB + aggA/aggB/xpreA/xpreB 270KB each
    char* ws = (char*)d_ws;
    size_t o = 0;
    auto alloc = [&](size_t bytes) { size_t r = o; o += (bytes + 255) & ~(size_t)255; return r; };
    float*  ybuf  = (float*)(ws + alloc((size_t)NB * LPAD * sizeof(float)));
    float4* mt    = (float4*)(ws + alloc(2048 * sizeof(float4)));
    float2* aggA  = (float2*)(ws + alloc((size_t)NB * NTW * NP * sizeof(float2)));
    float2* aggB  = (float2*)(ws + alloc((size_t)NB * NTW * NP * sizeof(float2)));
    float2* xpreA = (float2*)(ws + alloc((size_t)NB * NTW * NP * sizeof(float2)));
    float2* xpreB = (float2*)(ws + alloc((size_t)NB * NTW * NP * sizeof(float2)));

    dim3 blk(256), g(NTILE, NB);

    k_init     <<<8,  256, 0, stream>>>(mt, L);
    k_agg      <<<g,  blk, 0, stream>>>(audio, aggA, C, L);
    k_prefix<0><<<NB, blk, 0, stream>>>(aggA, xpreA, ybuf, C, L);
    k_full<0>  <<<g,  blk, 0, stream>>>(audio, ybuf, xpreA, aggB, mt, C, L);
    k_prefix<1><<<NB, blk, 0, stream>>>(aggB, xpreB, ybuf, C, L);
    k_full<1>  <<<g,  blk, 0, stream>>>(ybuf, out, xpreB, nullptr, mt, C, L);
}

// Round 14
// 123.340 us; speedup vs baseline: 1.1425x; 1.1364x over previous
//
#include <hip/hip_runtime.h>
#include <cmath>
#include <complex>

// sr=16000, band 500-7000, order 8 -> 16 poles = 8 real 2nd-order sections.
#define NB    32
#define LX    262144
#define PAD   51                      // padlen = 3*17
#define LTOT  (LX + 2 * PAD)          // 262246
#define CM    32                      // samples per chunk (= per thread)
#define F_PAD 8090                    // zero-input front pad
#define LPAD  (LTOT + F_PAD)          // 270336 = 33 * 8192 (tile-aligned)
#define CPB   256                     // threads per block
#define TILE  (CPB * CM)              // 8192 samples per block-tile
#define NTILE (LPAD / TILE)           // 33 block-tiles per row
#define WTS   (64 * CM)               // 2048 samples per wave-tile
#define NTW   (LPAD / WTS)            // 132 wave-tiles per row
#define NP    8
#define LDSR  34                      // floats per LDS lane-row (proven: low conflict)

struct CoeffsS { float a1[NP], a2[NP], b0[NP], b1[NP], g1a[NP], g1b[NP], c0; };
// lv[k][q] = (A_q^CM)^(2^k) = M0^(2^k); lv[6] = M0^64 = wave-tile transition
struct LvS { float lv[9][NP][4]; };

// ---------------------------------------------------------------------------
// init: build mt[t*8+q] = M0^t (t=0..255) via binary exponentiation.
__global__ void k_init(float4* __restrict__ mt, LvS L) {
    int id = blockIdx.x * 256 + threadIdx.x;          // 0..2047
    int t = id >> 3, q = id & 7;
    float m0 = 1.f, m1 = 0.f, m2 = 0.f, m3 = 1.f;
    for (int k = 0; k < 8; k++)
        if ((t >> k) & 1) {
            float a0 = L.lv[k][q][0], a1 = L.lv[k][q][1];
            float a2 = L.lv[k][q][2], a3 = L.lv[k][q][3];
            float n0 = a0 * m0 + a1 * m2, n1 = a0 * m1 + a1 * m3;
            float n2 = a2 * m0 + a3 * m2, n3 = a2 * m1 + a3 * m3;
            m0 = n0; m1 = n1; m2 = n2; m3 = n3;
        }
    mt[id] = make_float4(m0, m1, m2, m3);
}

// ---------------------------------------------------------------------------
// u-loader pass A: chunk c covers t' = c*CM..+CM, real t = t' - F_PAD.
__device__ __forceinline__ void load_uA(const float* __restrict__ x,
                                        float base, int c, float (&u)[CM]) {
    int t0 = c * CM - F_PAD;
    if (t0 >= PAD && t0 + CM <= PAD + LX) {
        const float* xs = x + (t0 - PAD);
#pragma unroll
        for (int m = 0; m < CM / 4; m++) {
            float4 v = *reinterpret_cast<const float4*>(xs + 4 * m);
            u[4 * m] = v.x - base; u[4 * m + 1] = v.y - base;
            u[4 * m + 2] = v.z - base; u[4 * m + 3] = v.w - base;
        }
    } else {
#pragma unroll
        for (int i = 0; i < CM; i++) {
            int t = t0 + i;
            float uu;
            if (t < 0) uu = 0.f;                        // front pad
            else {
                float e;
                if (t < PAD)            e = 2.0f * x[0] - x[PAD - t];
                else if (t < PAD + LX)  e = x[t - PAD];
                else                    e = 2.0f * x[LX - 1] - x[2 * LX + PAD - 2 - t];
                uu = e - base;
            }
            u[i] = uu;
        }
    }
}

// local chunk recurrence from zero state
__device__ __forceinline__ void local_states(const float (&u)[CM], const CoeffsS& C,
                                             float (&w1)[NP], float (&w2)[NP]) {
#pragma unroll
    for (int q = 0; q < NP; q++) { w1[q] = 0.f; w2[q] = 0.f; }
#pragma unroll
    for (int i = 0; i < CM; i++) {
        float uu = u[i];
#pragma unroll
        for (int q = 0; q < NP; q++) {
            float wt = fmaf(C.a1[q], w1[q], fmaf(C.a2[q], w2[q], uu));
            w2[q] = w1[q]; w1[q] = wt;
        }
    }
}

// wave inclusive affine scan, FORWARD (lane 0 first): lane l gets
// W_l = f_l + M0 f_{l-1} + ... + M0^l f_0.  lv[k] = M0^(2^k). No barriers.
__device__ __forceinline__ void wave_scan_fwd(int l, const LvS& L,
                                              float (&w1)[NP], float (&w2)[NP]) {
#pragma unroll
    for (int k = 0; k < 6; k++) {
        int d = 1 << k;
#pragma unroll
        for (int q = 0; q < NP; q++) {
            float o1 = __shfl_up(w1[q], d);
            float o2 = __shfl_up(w2[q], d);
            if (l >= d) {
                w1[q] = fmaf(L.lv[k][q][0], o1, fmaf(L.lv[k][q][1], o2, w1[q]));
                w2[q] = fmaf(L.lv[k][q][2], o1, fmaf(L.lv[k][q][3], o2, w2[q]));
            }
        }
    }
}

// wave reduce, REVERSE order (lane 63 first): lane 0 gets
// G = f_0 + M0 f_1 + ... + M0^63 f_63.
__device__ __forceinline__ void wave_reduce_rev(int l, const LvS& L,
                                                float (&w1)[NP], float (&w2)[NP]) {
#pragma unroll
    for (int k = 0; k < 6; k++) {
        int d = 1 << k;
#pragma unroll
        for (int q = 0; q < NP; q++) {
            float o1 = __shfl_down(w1[q], d);
            float o2 = __shfl_down(w2[q], d);
            if (l + d <= 63) {
                w1[q] = fmaf(L.lv[k][q][0], o1, fmaf(L.lv[k][q][1], o2, w1[q]));
                w2[q] = fmaf(L.lv[k][q][2], o1, fmaf(L.lv[k][q][3], o2, w2[q]));
            }
        }
    }
}

// ---------------------------------------------------------------------------
// K1 (pass A): per-WAVE-tile aggregates from zero init. No LDS, no barriers.
__global__ __launch_bounds__(256) void k_agg(const float* __restrict__ audio,
                                             float2* __restrict__ agg,
                                             CoeffsS C, LvS L) {
    int tid = threadIdx.x, tx = blockIdx.x, b = blockIdx.y;
    int wv = tid >> 6, l = tid & 63;
    int wt = tx * 4 + wv;
    const float* x = audio + (size_t)b * LX;
    float base = 2.0f * x[0] - x[PAD];
    float u[CM];
    load_uA(x, base, tx * CPB + tid, u);
    float w1[NP], w2[NP];
    local_states(u, C, w1, w2);
    wave_scan_fwd(l, L, w1, w2);
    if (l == 63) {
#pragma unroll
        for (int q = 0; q < NP; q++)
            agg[(size_t)(b * NTW + wt) * NP + q] = make_float2(w1[q], w2[q]);
    }
}

// ---------------------------------------------------------------------------
// K2: per-row serial walk over NTW wave aggregates (LDS-staged) -> exclusive
// per-wave entry states X. CORR=1 (pass B): subtract base*g2048 per aggregate.
template <int CORR>
__global__ __launch_bounds__(256) void k_prefix(const float2* __restrict__ agg,
                                                float2* __restrict__ xpre,
                                                const float* __restrict__ ybuf,
                                                CoeffsS C, LvS L) {
    __shared__ float2 sa[NTW * NP];       // 8448 B
    int b = blockIdx.x, tid = threadIdx.x;
    const float2* ab = agg + (size_t)b * NTW * NP;
    for (int id = tid; id < NTW * NP; id += 256) sa[id] = ab[id];
    __syncthreads();
    if (tid < NP) {
        int q = tid;
        float B0 = L.lv[6][q][0], B1 = L.lv[6][q][1];   // M0^64 = A^2048
        float B2 = L.lv[6][q][2], B3 = L.lv[6][q][3];
        float cga = 0.f, cgb = 0.f;
        if (CORR) {
            float base = ybuf[(size_t)b * LPAD];
            cga = base * C.g1a[q]; cgb = base * C.g1b[q];
        }
        float X1 = 0.f, X2 = 0.f;
        for (int t = 0; t < NTW; t++) {
            xpre[(size_t)(b * NTW + t) * NP + q] = make_float2(X1, X2);
            float2 f = sa[t * NP + q];
            float n1 = fmaf(B0, X1, fmaf(B1, X2, f.x - cga));
            float n2 = fmaf(B2, X1, fmaf(B3, X2, f.y - cgb));
            X1 = n1; X2 = n2;
        }
    }
}

// ---------------------------------------------------------------------------
// K3: wave scan (no barriers); entry from precomputed per-wave X; replay;
// block-staged coalesced store (1 barrier).
// PASS 0: in=audio -> ybuf reversed; also emits raw pass-B wave aggregates.
// PASS 1: in=ybuf -> final out (un-reverse + trim PAD).
template <int PASS>
__global__ __launch_bounds__(256) void k_full(const float* __restrict__ in,
                                              float* __restrict__ outp,
                                              const float2* __restrict__ xpre,
                                              float2* __restrict__ aggB,
                                              const float4* __restrict__ mt,
                                              CoeffsS C, LvS L) {
    __shared__ __align__(16) float lds[CPB * LDSR];   // 34816 B
    int tid = threadIdx.x, tx = blockIdx.x, b = blockIdx.y;
    int wv = tid >> 6, l = tid & 63;
    int wt = tx * 4 + wv;
    int c = tx * CPB + tid;

    // ---- load u ----
    float u[CM];
    if (PASS == 0) {
        const float* x = in + (size_t)b * LX;
        float base = 2.0f * x[0] - x[PAD];
        load_uA(x, base, c, u);
    } else {
        const float* yb = in + (size_t)b * LPAD;
        float base = yb[0];               // = y[LTOT-1]
        const float* ys = yb + (size_t)c * CM;
#pragma unroll
        for (int m = 0; m < CM / 4; m++) {
            float4 v = *reinterpret_cast<const float4*>(ys + 4 * m);
            u[4 * m] = v.x - base; u[4 * m + 1] = v.y - base;
            u[4 * m + 2] = v.z - base; u[4 * m + 3] = v.w - base;
        }
    }

    // ---- local states + wave scan (registers, no barriers) ----
    float w1[NP], w2[NP];
    local_states(u, C, w1, w2);
    wave_scan_fwd(l, L, w1, w2);

    // ---- entry = (exclusive within wave) + M0^l * X_wave; replay ----
#pragma unroll
    for (int q = 0; q < NP; q++) {
        float a = __shfl_up(w1[q], 1), bb = __shfl_up(w2[q], 1);
        float e1 = (l == 0) ? 0.f : a;
        float e2 = (l == 0) ? 0.f : bb;
        float2 X = xpre[(size_t)(b * NTW + wt) * NP + q];
        float4 m4 = mt[l * NP + q];
        w1[q] = fmaf(m4.x, X.x, fmaf(m4.y, X.y, e1));
        w2[q] = fmaf(m4.z, X.x, fmaf(m4.w, X.y, e2));
    }
#pragma unroll
    for (int i = 0; i < CM; i++) {
        float uu = u[i];
        float y = C.c0 * uu;
#pragma unroll
        for (int q = 0; q < NP; q++) {
            float wt2 = fmaf(C.a1[q], w1[q], fmaf(C.a2[q], w2[q], uu));
            y = fmaf(C.b0[q], wt2, fmaf(C.b1[q], w1[q], y));
            w2[q] = w1[q]; w1[q] = wt2;
        }
        u[i] = y;                          // u now holds y
    }

    if (PASS == 0) {
        // ---- fused raw pass-B wave aggregates (registers + shfl only) ----
        float t1[NP], t2[NP];
#pragma unroll
        for (int q = 0; q < NP; q++) { t1[q] = 0.f; t2[q] = 0.f; }
#pragma unroll
        for (int i = CM - 1; i >= 0; --i) {   // pass-B order within chunk
            float wvv = u[i];
#pragma unroll
            for (int q = 0; q < NP; q++) {
                float wt2 = fmaf(C.a1[q], t1[q], fmaf(C.a2[q], t2[q], wvv));
                t2[q] = t1[q]; t1[q] = wt2;
            }
        }
        wave_reduce_rev(l, L, t1, t2);
        if (l == 0) {
            int kB = NTW - 1 - wt;            // pass-B wave-tile index
#pragma unroll
            for (int q = 0; q < NP; q++)
                aggB[(size_t)(b * NTW + kB) * NP + q] = make_float2(t1[q], t2[q]);
        }
    }

    // ---- stage y to LDS; barrier; coalesced store (round-10-proven) ----
    if (PASS == 0) {
#pragma unroll
        for (int k = 0; k < CM / 2; k++)
            *reinterpret_cast<float2*>(&lds[tid * LDSR + 2 * k]) =
                make_float2(u[2 * k], u[2 * k + 1]);
    } else {
#pragma unroll
        for (int i = 0; i < CM; i++) lds[tid * LDSR + i] = u[i];
    }
    __syncthreads();

    if (PASS == 0) {
        // coalesced REVERSED store: ybuf[k] = y[LPAD-1-t']
        float4* yb4 = reinterpret_cast<float4*>(
            outp + (size_t)b * LPAD + (size_t)(NTILE - 1 - tx) * TILE);
#pragma unroll
        for (int m = 0; m < 8; m++) {
            int o4 = m * CPB + tid;            // 0..2047
            int ts = 255 - (o4 >> 3);
            int ih = 31 - 4 * (o4 & 7);
            float2 a  = *reinterpret_cast<const float2*>(&lds[ts * LDSR + ih - 1]);
            float2 b2 = *reinterpret_cast<const float2*>(&lds[ts * LDSR + ih - 3]);
            yb4[o4] = make_float4(a.y, a.x, b2.y, b2.x);
        }
    } else {
        // out[j] = y2[s], j = (LTOT-1-PAD) - s  (un-reverse + trim PAD)
        float* ob = outp + (size_t)b * LX;
        int J0 = (LTOT - 1 - PAD) - tx * TILE;
#pragma unroll
        for (int m = 0; m < CM; m++) {
            int o = m * CPB + tid;
            int j = J0 - o;
            if (j >= 0 && j < LX)
                ob[j] = lds[(o >> 5) * LDSR + (o & 31)];
        }
    }
}

// ---------------------------------------------------------------------------
// Host: scipy butter(8,[500,7000]/8000,'bandpass') -> real 2nd-order sections
// + chunk-transition (A^32) power levels + exact 2048-step const-input pair.
static void compute_coeffs(CoeffsS& C, LvS& L) {
    using cd = std::complex<double>;
    const int N = 8;
    const double sr = 16000.0, lo = 500.0, hi = 7000.0, fs = 2.0;
    double w0 = 2.0 * fs * std::tan(M_PI * (2.0 * lo / sr) / fs);
    double w1 = 2.0 * fs * std::tan(M_PI * (2.0 * hi / sr) / fs);
    double bw = w1 - w0, wo = std::sqrt(w0 * w1);
    cd pbp[16];
    for (int k = 0; k < N; k++) {
        int m = -N + 1 + 2 * k;
        cd pl = -std::exp(cd(0.0, M_PI * m / (2.0 * N)));
        pl *= bw / 2.0;
        cd s = std::sqrt(pl * pl - cd(wo * wo, 0.0));
        pbp[k] = pl + s; pbp[k + N] = pl - s;
    }
    double kbp = std::pow(bw, (double)N);
    const double fs2 = 4.0;
    cd pd[16], denom = 1.0;
    for (int i = 0; i < 16; i++) {
        pd[i] = (cd(fs2, 0.0) + pbp[i]) / (cd(fs2, 0.0) - pbp[i]);
        denom *= (cd(fs2, 0.0) - pbp[i]);
    }
    double kd = kbp * std::real(cd(std::pow(fs2, 8.0), 0.0) / denom);
    cd prodp = 1.0;
    for (int i = 0; i < 16; i++) prodp *= pd[i];
    cd c0 = cd(kd, 0.0) / prodp;
    int n = 0;
    for (int i = 0; i < 16; i++) {
        if (pd[i].imag() <= 0.0) continue;
        cd inv = 1.0 / pd[i];
        cd t1 = cd(1.0, 0.0) - inv, t2 = cd(1.0, 0.0) + inv;
        cd numr = cd(kd, 0.0);
        for (int k = 0; k < 8; k++) numr *= t1;
        for (int k = 0; k < 8; k++) numr *= t2;
        cd den = 1.0;
        for (int j = 0; j < 16; j++)
            if (j != i) den *= (cd(1.0, 0.0) - pd[j] * inv);
        cd r2 = 2.0 * numr / den;             // conjugate pair folded
        if (n < NP) {
            double a1 = 2.0 * pd[i].real();
            double a2 = -std::norm(pd[i]);
            C.a1[n] = (float)a1; C.a2[n] = (float)a2;
            C.b0[n] = (float)r2.real();
            C.b1[n] = (float)(-(r2.real() * pd[i].real() + r2.imag() * pd[i].imag()));
            // exact 2048-step constant-input response pair (prefixB correction)
            double gw1 = 0.0, gw2 = 0.0;
            for (int k = 0; k < 2048; k++) {
                double gt = a1 * gw1 + a2 * gw2 + 1.0; gw2 = gw1; gw1 = gt;
            }
            C.g1a[n] = (float)gw1; C.g1b[n] = (float)gw2;
            double M[4] = { a1, a2, 1.0, 0.0 };       // A = [[a1,a2],[1,0]]
            for (int s = 0; s < 5; s++) {             // M0 = A^32
                double q0 = M[0] * M[0] + M[1] * M[2], q1 = M[0] * M[1] + M[1] * M[3];
                double q2 = M[2] * M[0] + M[3] * M[2], q3 = M[2] * M[1] + M[3] * M[3];
                M[0] = q0; M[1] = q1; M[2] = q2; M[3] = q3;
            }
            for (int k = 0; k < 9; k++) {             // lv[k] = M0^(2^k)
                for (int j = 0; j < 4; j++) L.lv[k][n][j] = (float)M[j];
                double q0 = M[0] * M[0] + M[1] * M[2], q1 = M[0] * M[1] + M[1] * M[3];
                double q2 = M[2] * M[0] + M[3] * M[2], q3 = M[2] * M[1] + M[3] * M[3];
                M[0] = q0; M[1] = q1; M[2] = q2; M[3] = q3;
            }
            n++;
        }
    }
    C.c0 = (float)c0.real();
}

extern "C" void kernel_launch(void* const* d_in, const int* in_sizes, int n_in,
                              void* d_out, int out_size, void* d_ws, size_t ws_size,
                              hipStream_t stream) {
    const float* audio = (const float*)d_in[0];
    float* out = (float*)d_out;

    CoeffsS C; LvS L;
    compute_coeffs(C, L);

    // ws: ybuf 34.6MB + mt 32KB + aggA/aggB/xpreA/xpreB 270KB each
    char* ws = (char*)d_ws;
    size_t o = 0;
    auto alloc = [&](size_t bytes) { size_t r = o; o += (bytes + 255) & ~(size_t)255; return r; };
    float*  ybuf  = (float*)(ws + alloc((size_t)NB * LPAD * sizeof(float)));
    float4* mt    = (float4*)(ws + alloc(2048 * sizeof(float4)));
    float2* aggA  = (float2*)(ws + alloc((size_t)NB * NTW * NP * sizeof(float2)));
    float2* aggB  = (float2*)(ws + alloc((size_t)NB * NTW * NP * sizeof(float2)));
    float2* xpreA = (float2*)(ws + alloc((size_t)NB * NTW * NP * sizeof(float2)));
    float2* xpreB = (float2*)(ws + alloc((size_t)NB * NTW * NP * sizeof(float2)));

    dim3 blk(256), g(NTILE, NB);

    k_init     <<<8,  256, 0, stream>>>(mt, L);
    k_agg      <<<g,  blk, 0, stream>>>(audio, aggA, C, L);
    k_prefix<0><<<NB, blk, 0, stream>>>(aggA, xpreA, ybuf, C, L);
    k_full<0>  <<<g,  blk, 0, stream>>>(audio, ybuf, xpreA, aggB, mt, C, L);
    k_prefix<1><<<NB, blk, 0, stream>>>(aggB, xpreB, ybuf, C, L);
    k_full<1>  <<<g,  blk, 0, stream>>>(ybuf, out, xpreB, nullptr, mt, C, L);
}